// Round 7
// baseline (179.159 us; speedup 1.0000x reference)
//
#include <hip/hip_runtime.h>
#include <math.h>

// TSC (order-3) particle-to-mesh deposition.
//
// Fast path (C==8, n even, n<=256): per-1x1-column fixed-capacity bin lists
// of PACKED 48B records (pos.xyz + 8 emb), then PERSISTENT-BLOCK slab
// deposit: 2048 blocks, each owning a contiguous chunk of (x, y-pair) tiles.
// Per tile: zero 12.8KB LDS -> LDS-atomic deposit -> barrier -> ds_read +
// fire-and-forget nontemporal stores -> barrier -> next tile. Stores drain
// during the NEXT tile's compute (no vmcnt wait), keeping the HBM write pipe
// at high duty cycle -- the launch-per-tile designs (r1/r3/r4/r6) were
// phase-locked (co-resident identical blocks burst stores simultaneously,
// then all go quiet) and stalled at ~1.7-2 TB/s effective.
//
// Fallbacks: interleaved-atomic two-phase (C==8), generic planar atomics.

#define KColCAP 16   // records per 1x1 column bin (lambda ~2.5)
#define TYS 2        // y extent of slab tile
#define BLK 128      // threads per block (2 waves)
#define BPCU 8       // persistent blocks per CU

// native 16B vector type usable with __builtin_nontemporal_store
typedef float nfloat4 __attribute__((ext_vector_type(4)));

// TSC weight for axis offset o in {-1,0,+1} at fractional distance d in [-0.5,0.5]
__device__ __forceinline__ float tsc_w(int o, float d) {
    float t = 0.5f + (float)o * d;
    return (o == 0) ? (0.75f - d * d) : (0.5f * t * t);
}

__device__ __forceinline__ float inv_spacing(const float* __restrict__ cell, int n) {
    float tr = cell[0] + cell[4] + cell[8];
    return (3.0f * (float)n) / tr;
}

// ---------------- binning: packed records into 1x1-column lists ----------------

__global__ __launch_bounds__(256) void fill_recs(
    const float* __restrict__ pos, const float* __restrict__ cell,
    const float* __restrict__ emb,
    int* __restrict__ counts, int* __restrict__ ovf_cnt,
    float4* __restrict__ binrec, int* __restrict__ ovf,
    int N, int n)
{
    int i = blockIdx.x * blockDim.x + threadIdx.x;
    if (i >= N) return;
    float inv_sp = inv_spacing(cell, n);
    float px = pos[3 * i + 0] * inv_sp;
    float py = pos[3 * i + 1] * inv_sp;
    float pz = pos[3 * i + 2] * inv_sp;
    int cx = (int)rintf(px); if (cx >= n) cx -= n; else if (cx < 0) cx += n;
    int cy = (int)rintf(py); if (cy >= n) cy -= n; else if (cy < 0) cy += n;
    int bin = cx * n + cy;
    int slot = atomicAdd(&counts[bin], 1);
    if (slot < KColCAP) {
        const float4* e4 = (const float4*)(emb + (size_t)i * 8);
        float4* r = binrec + (size_t)(bin * KColCAP + slot) * 3;
        r[0] = make_float4(px, py, pz, 0.0f);
        r[1] = e4[0];
        r[2] = e4[1];
    } else {
        int o = atomicAdd(ovf_cnt, 1);
        ovf[o] = i;   // ovf sized N: cannot overflow
    }
}

// ---------------- persistent-block slab deposit ----------------
// Tile = (x, y0..y0+1, all z). LDS: [8ch][TYS][n] floats (linear == output
// order per channel). Bins: (x-1..x+1) x (y0-1..y0+2) = 12 columns; every
// listed atom is relevant; single in-tile x-corner per atom.

__global__ __launch_bounds__(BLK) void deposit_persist(
    const float4* __restrict__ binrec, const int* __restrict__ counts,
    float* __restrict__ out, int n, int nyg, int ntiles, int tpb)
{
    extern __shared__ float lds[];
    const int tid = threadIdx.x;
    const int plane = TYS * n;            // floats per channel
    const int q4 = plane >> 2;            // float4s per channel
    const int nf4 = 8 * q4;               // total float4s in tile
    const int half = n >> 1;
    const size_t n3 = (size_t)n * n * n;

    __shared__ int s_base[12], s_cnt[12], s_pref[13];

    int t0 = blockIdx.x * tpb;
    int t1 = t0 + tpb; if (t1 > ntiles) t1 = ntiles;

    for (int t = t0; t < t1; ++t) {
        const int x = t / nyg, yg = t - x * nyg;
        const int y0 = yg * TYS;

        // zero tile
        for (int i = tid; i < nf4; i += BLK)
            ((nfloat4*)lds)[i] = (nfloat4)(0.f);

        if (tid < 12) {
            int dxb = tid / 4 - 1;            // -1,0,1
            int jy  = tid & 3;                // 0..3
            int xb = x + dxb; if (xb < 0) xb += n; else if (xb >= n) xb -= n;
            int yb = y0 - 1 + jy; if (yb < 0) yb += n; else if (yb >= n) yb -= n;
            int bin = xb * n + yb;
            s_base[tid] = bin * KColCAP;
            int c = counts[bin];
            s_cnt[tid] = (c < KColCAP) ? c : KColCAP;
        }
        __syncthreads();
        if (tid == 0) {
            int r = 0;
            #pragma unroll
            for (int j = 0; j < 12; ++j) { s_pref[j] = r; r += s_cnt[j]; }
            s_pref[12] = r;
        }
        __syncthreads();
        const int tot = s_pref[12];

        for (int v = tid; v < tot; v += BLK) {
            int j = 0;
            #pragma unroll
            for (int k = 1; k < 12; ++k) j += (v >= s_pref[k]);
            const float4* rp = binrec + (size_t)(s_base[j] + (v - s_pref[j])) * 3;
            float4 P  = rp[0];
            float4 e0 = rp[1];
            float4 e1 = rp[2];

            int cx = (int)rintf(P.x); float dx = P.x - (float)cx;
            int cy = (int)rintf(P.y); float dy = P.y - (float)cy;
            int cz = (int)rintf(P.z); float dz = P.z - (float)cz;
            if (cx >= n) cx -= n; else if (cx < 0) cx += n;
            if (cy >= n) cy -= n; else if (cy < 0) cy += n;
            if (cz >= n) cz -= n; else if (cz < 0) cz += n;

            int rx = cx - x;  if (rx > half) rx -= n; else if (rx < -half) rx += n;
            int ry = cy - y0; if (ry > half) ry -= n; else if (ry < -half) ry += n;

            float wx = tsc_w(-rx, dx);   // single in-tile x corner

            float wys[3] = { wx * tsc_w(-1, dy), wx * tsc_w(0, dy), wx * tsc_w(1, dy) };
            float wzs[3] = { tsc_w(-1, dz), tsc_w(0, dz), tsc_w(1, dz) };
            int lz0 = cz - 1; if (lz0 < 0) lz0 += n;
            int lz2 = cz + 1; if (lz2 >= n) lz2 -= n;
            int lzs[3] = { lz0, cz, lz2 };

            #pragma unroll
            for (int kb = 0; kb < 3; ++kb) {
                int ly = ry + kb - 1;
                if (ly < 0 || ly >= TYS) continue;
                float wvy = wys[kb];
                #pragma unroll
                for (int kc = 0; kc < 3; ++kc) {
                    float w = wvy * wzs[kc];
                    float* p = lds + ly * n + lzs[kc];
                    atomicAdd(p + 0 * plane, w * e0.x);
                    atomicAdd(p + 1 * plane, w * e0.y);
                    atomicAdd(p + 2 * plane, w * e0.z);
                    atomicAdd(p + 3 * plane, w * e0.w);
                    atomicAdd(p + 4 * plane, w * e1.x);
                    atomicAdd(p + 5 * plane, w * e1.y);
                    atomicAdd(p + 6 * plane, w * e1.z);
                    atomicAdd(p + 7 * plane, w * e1.w);
                }
            }
        }
        __syncthreads();

        // writeout: lds[ch][0..plane) is linear in out[ch][x][y0*n ..).
        // Fire-and-forget nontemporal stores; they drain under the next
        // tile's zero/deposit phases.
        float* outb = out + (size_t)x * n * n + (size_t)y0 * n;
        for (int i = tid; i < nf4; i += BLK) {
            int ch = i / q4;
            int q  = i - ch * q4;
            nfloat4 v = ((const nfloat4*)lds)[i];
            __builtin_nontemporal_store(
                v, (nfloat4*)(outb + (size_t)ch * n3) + q);
        }
        __syncthreads();   // LDS reads complete before next tile's zero
    }
}

// overflow cleanup: global planar atomics for atoms that missed their bin list
__global__ __launch_bounds__(256) void deposit_overflow(
    const float* __restrict__ pos, const float* __restrict__ cell,
    const float* __restrict__ emb, const int* __restrict__ ovf_cnt,
    const int* __restrict__ ovf, float* __restrict__ out, int n)
{
    int m = *ovf_cnt;
    int i = blockIdx.x * blockDim.x + threadIdx.x;
    if (i >= m) return;
    int ai = ovf[i];
    float inv_sp = inv_spacing(cell, n);
    float p[3], d[3]; int c0[3];
    #pragma unroll
    for (int kk = 0; kk < 3; ++kk) {
        p[kk] = pos[3 * ai + kk] * inv_sp;
        c0[kk] = (int)rintf(p[kk]);
        d[kk] = p[kk] - (float)c0[kk];
    }
    float w[3][3];
    #pragma unroll
    for (int kk = 0; kk < 3; ++kk) {
        float dd = d[kk];
        w[kk][0] = tsc_w(-1, dd); w[kk][1] = tsc_w(0, dd); w[kk][2] = tsc_w(1, dd);
    }
    int W[3][3];
    #pragma unroll
    for (int kk = 0; kk < 3; ++kk)
        #pragma unroll
        for (int a = 0; a < 3; ++a) {
            int v = c0[kk] - 1 + a; if (v < 0) v += n; else if (v >= n) v -= n;
            W[kk][a] = v;
        }
    size_t n3 = (size_t)n * n * n;
    const float4* e4 = (const float4*)(emb + (size_t)ai * 8);
    float4 e0 = e4[0], e1 = e4[1];
    float e[8] = {e0.x, e0.y, e0.z, e0.w, e1.x, e1.y, e1.z, e1.w};
    for (int a = 0; a < 3; ++a)
        for (int bq = 0; bq < 3; ++bq)
            for (int cq = 0; cq < 3; ++cq) {
                float wt = w[0][a] * w[1][bq] * w[2][cq];
                size_t g = ((size_t)W[0][a] * n + W[1][bq]) * n + W[2][cq];
                #pragma unroll
                for (int ch = 0; ch < 8; ++ch)
                    atomicAdd(out + (size_t)ch * n3 + g, wt * e[ch]);
            }
}

// ---------------- fallback: interleaved atomics + transpose ----------------

__global__ __launch_bounds__(256) void deposit_tsc8_ilv(
    const float* __restrict__ pos,
    const float* __restrict__ cell,
    const float* __restrict__ emb,
    float* __restrict__ ws,
    int total, int n)
{
    int t = blockIdx.x * blockDim.x + threadIdx.x;
    if (t >= total) return;
    int atom = t / 27;
    int c    = t - atom * 27;
    int a    = c / 9;
    int rem  = c - a * 9;
    int b    = rem / 3;
    int cc   = rem - b * 3;

    float inv_sp = inv_spacing(cell, n);

    float px = pos[3 * atom + 0] * inv_sp;
    float py = pos[3 * atom + 1] * inv_sp;
    float pz = pos[3 * atom + 2] * inv_sp;

    int cx = (int)rintf(px);  float dx = px - (float)cx;
    int cy = (int)rintf(py);  float dy = py - (float)cy;
    int cz = (int)rintf(pz);  float dz = pz - (float)cz;

    float w = tsc_w(a - 1, dx) * tsc_w(b - 1, dy) * tsc_w(cc - 1, dz);

    int x = cx - 1 + a;  if (x < 0) x += n; else if (x >= n) x -= n;
    int y = cy - 1 + b;  if (y < 0) y += n; else if (y >= n) y -= n;
    int z = cz - 1 + cc; if (z < 0) z += n; else if (z >= n) z -= n;

    const float4* e4 = (const float4*)(emb + (size_t)atom * 8);
    float4 e0 = e4[0], e1 = e4[1];

    float* p = ws + ((size_t)((x * n + y) * n + z)) * 8;
    atomicAdd(p + 0, w * e0.x);
    atomicAdd(p + 1, w * e0.y);
    atomicAdd(p + 2, w * e0.z);
    atomicAdd(p + 3, w * e0.w);
    atomicAdd(p + 4, w * e1.x);
    atomicAdd(p + 5, w * e1.y);
    atomicAdd(p + 6, w * e1.z);
    atomicAdd(p + 7, w * e1.w);
}

__global__ __launch_bounds__(256) void transpose_ilv8(
    const float* __restrict__ ws, float* __restrict__ out, int n3)
{
    int t = blockIdx.x * blockDim.x + threadIdx.x;
    int g0 = t * 4;
    if (g0 >= n3) return;
    const float4* w4 = (const float4*)(ws + (size_t)g0 * 8);
    float4 r0 = w4[0], r1 = w4[1];
    float4 r2 = w4[2], r3 = w4[3];
    float4 r4 = w4[4], r5 = w4[5];
    float4 r6 = w4[6], r7 = w4[7];

    *(float4*)(out + (size_t)0 * n3 + g0) = make_float4(r0.x, r2.x, r4.x, r6.x);
    *(float4*)(out + (size_t)1 * n3 + g0) = make_float4(r0.y, r2.y, r4.y, r6.y);
    *(float4*)(out + (size_t)2 * n3 + g0) = make_float4(r0.z, r2.z, r4.z, r6.z);
    *(float4*)(out + (size_t)3 * n3 + g0) = make_float4(r0.w, r2.w, r4.w, r6.w);
    *(float4*)(out + (size_t)4 * n3 + g0) = make_float4(r1.x, r3.x, r5.x, r7.x);
    *(float4*)(out + (size_t)5 * n3 + g0) = make_float4(r1.y, r3.y, r5.y, r7.y);
    *(float4*)(out + (size_t)6 * n3 + g0) = make_float4(r1.z, r3.z, r5.z, r7.z);
    *(float4*)(out + (size_t)7 * n3 + g0) = make_float4(r1.w, r3.w, r5.w, r7.w);
}

// ---------------- fallback: generic planar atomics ----------------

__global__ __launch_bounds__(256) void deposit_tsc_gen(
    const float* __restrict__ pos,
    const float* __restrict__ cell,
    const float* __restrict__ emb,
    float* __restrict__ out,
    int N, int n, int C)
{
    int i = blockIdx.x * blockDim.x + threadIdx.x;
    if (i >= N) return;

    float inv_sp = inv_spacing(cell, n);

    float p[3], d[3];
    int c0[3];
    #pragma unroll
    for (int k = 0; k < 3; ++k) {
        p[k] = pos[3 * i + k] * inv_sp;
        c0[k] = (int)rintf(p[k]);
        d[k] = p[k] - (float)c0[k];
    }
    float w[3][3];
    #pragma unroll
    for (int k = 0; k < 3; ++k) {
        float dd = d[k], d2 = dd * dd;
        w[k][0] = 0.125f * (1.0f - 4.0f * dd + 4.0f * d2);
        w[k][1] = 0.25f  * (3.0f - 4.0f * d2);
        w[k][2] = 0.125f * (1.0f + 4.0f * dd + 4.0f * d2);
    }
    int W[3][3];
    #pragma unroll
    for (int k = 0; k < 3; ++k) {
        #pragma unroll
        for (int a = 0; a < 3; ++a) {
            int v = c0[k] - 1 + a; if (v < 0) v += n; else if (v >= n) v -= n;
            W[k][a] = v;
        }
    }
    int n3 = n * n * n;
    for (int a = 0; a < 3; ++a)
        for (int b = 0; b < 3; ++b)
            for (int cc = 0; cc < 3; ++cc) {
                float wt = w[0][a] * w[1][b] * w[2][cc];
                int g = (W[0][a] * n + W[1][b]) * n + W[2][cc];
                for (int ch = 0; ch < C; ++ch)
                    atomicAdd(out + (size_t)ch * n3 + g, wt * emb[(size_t)i * C + ch]);
            }
}

extern "C" void kernel_launch(void* const* d_in, const int* in_sizes, int n_in,
                              void* d_out, int out_size, void* d_ws, size_t ws_size,
                              hipStream_t stream) {
    const float* pos  = (const float*)d_in[0];
    const float* cell = (const float*)d_in[1];
    const float* emb  = (const float*)d_in[2];
    float* out = (float*)d_out;
    float* ws  = (float*)d_ws;

    int N = in_sizes[0] / 3;
    int C = in_sizes[2] / N;
    long long n3l = (long long)out_size / C;
    int n = (int)llroundf(cbrtf((float)n3l));
    int n3 = (int)n3l;

    int block = 256;

    // ---- persistent-block slab fast path ----
    {
        int nb = n * n;
        size_t lds_bytes = (size_t)8 * TYS * n * sizeof(float);   // 64n B
        size_t rec_off = (((size_t)nb + 4 + (size_t)N) * sizeof(int) + 15) & ~(size_t)15;
        size_t need = rec_off + (size_t)nb * KColCAP * 48;
        bool slab_ok = (C == 8) && (n % TYS == 0) && n >= 8 && n <= 256
                       && lds_bytes <= 64 * 1024
                       && ws_size >= need
                       && ((long long)n * n * n == n3l);
        if (slab_ok) {
            int* counts  = (int*)d_ws;
            int* ovf_cnt = counts + nb;
            int* ovf     = counts + nb + 4;
            float4* binrec = (float4*)((char*)d_ws + rec_off);

            (void)hipMemsetAsync(counts, 0, (size_t)(nb + 4) * sizeof(int), stream);
            fill_recs<<<(N + block - 1) / block, block, 0, stream>>>(
                pos, cell, emb, counts, ovf_cnt, binrec, ovf, N, n);

            int nyg = n / TYS;
            int ntiles = n * nyg;
            int nblocks = 256 * BPCU;
            if (nblocks > ntiles) nblocks = ntiles;
            int tpb = (ntiles + nblocks - 1) / nblocks;
            deposit_persist<<<nblocks, BLK, lds_bytes, stream>>>(
                binrec, counts, out, n, nyg, ntiles, tpb);

            deposit_overflow<<<(N + block - 1) / block, block, 0, stream>>>(
                pos, cell, emb, ovf_cnt, ovf, out, n);
            return;
        }
    }

    // ---- fallback: interleaved atomics + transpose ----
    size_t need = (size_t)out_size * sizeof(float);
    if (C == 8 && ws_size >= need && (n3 % 4) == 0) {
        (void)hipMemsetAsync(d_ws, 0, need, stream);
        int total = N * 27;
        deposit_tsc8_ilv<<<(total + block - 1) / block, block, 0, stream>>>(
            pos, cell, emb, ws, total, n);
        int tthreads = n3 / 4;
        transpose_ilv8<<<(tthreads + block - 1) / block, block, 0, stream>>>(
            ws, out, n3);
    } else {
        (void)hipMemsetAsync(d_out, 0, (size_t)out_size * sizeof(float), stream);
        int grid = (N + block - 1) / block;
        deposit_tsc_gen<<<grid, block, 0, stream>>>(pos, cell, emb, out, N, n, C);
    }
}

// Round 8
// 162.441 us; speedup vs baseline: 1.1029x; 1.1029x over previous
//
#include <hip/hip_runtime.h>
#include <math.h>

// TSC (order-3) particle-to-mesh deposition.
//
// Fast path (C==8, n even, n<=256): per-1x1-column fixed-capacity bin lists
// of PACKED 48B records, then PRODUCER/CONSUMER slab deposit:
//   256-thread blocks; waves 0-1 = producers (zero LDS, load counts/binrec,
//   LDS-atomic deposit), waves 2-3 = consumers (ds_read + nontemporal store
//   of the previous tile). Raw s_barrier + lgkmcnt-only waits: consumer
//   waves issue NO loads and NO vmcnt waits ever, so their stores stay in
//   flight across the whole kernel (vmcnt retires in order -- in previous
//   designs every load-use / __syncthreads drained all outstanding stores,
//   capping write BW at ~1.7 TB/s by Little's law).
//   Double-buffered LDS [2][8][CSTR] with CSTR = TYS*n+4 (mod 32 = 20 at
//   n=200 -> 8-channel atomic walk hits 8 distinct banks). Strided tile
//   order keeps concurrent blocks' writes address-adjacent.
//
// Fallbacks: interleaved-atomic two-phase (C==8), generic planar atomics.

#define KColCAP 16   // records per 1x1 column bin (lambda ~2.5)
#define TYS 2        // y extent of slab tile
#define BLK 256      // 4 waves: 0-1 producers, 2-3 consumers
#define NBLK 1536    // ~6 blocks/CU

typedef float nfloat4 __attribute__((ext_vector_type(4)));

__device__ __forceinline__ void block_sync_lds() {
    __builtin_amdgcn_sched_barrier(0);
    asm volatile("s_waitcnt lgkmcnt(0)" ::: "memory");
    __builtin_amdgcn_s_barrier();
    __builtin_amdgcn_sched_barrier(0);
}

// TSC weight for axis offset o in {-1,0,+1} at fractional distance d in [-0.5,0.5]
__device__ __forceinline__ float tsc_w(int o, float d) {
    float t = 0.5f + (float)o * d;
    return (o == 0) ? (0.75f - d * d) : (0.5f * t * t);
}

__device__ __forceinline__ float inv_spacing(const float* __restrict__ cell, int n) {
    float tr = cell[0] + cell[4] + cell[8];
    return (3.0f * (float)n) / tr;
}

// ---------------- binning: packed records into 1x1-column lists ----------------

__global__ __launch_bounds__(256) void fill_recs(
    const float* __restrict__ pos, const float* __restrict__ cell,
    const float* __restrict__ emb,
    int* __restrict__ counts, int* __restrict__ ovf_cnt,
    float4* __restrict__ binrec, int* __restrict__ ovf,
    int N, int n)
{
    int i = blockIdx.x * blockDim.x + threadIdx.x;
    if (i >= N) return;
    float inv_sp = inv_spacing(cell, n);
    float px = pos[3 * i + 0] * inv_sp;
    float py = pos[3 * i + 1] * inv_sp;
    float pz = pos[3 * i + 2] * inv_sp;
    int cx = (int)rintf(px); if (cx >= n) cx -= n; else if (cx < 0) cx += n;
    int cy = (int)rintf(py); if (cy >= n) cy -= n; else if (cy < 0) cy += n;
    int bin = cx * n + cy;
    int slot = atomicAdd(&counts[bin], 1);
    if (slot < KColCAP) {
        const float4* e4 = (const float4*)(emb + (size_t)i * 8);
        float4* r = binrec + (size_t)(bin * KColCAP + slot) * 3;
        r[0] = make_float4(px, py, pz, 0.0f);
        r[1] = e4[0];
        r[2] = e4[1];
    } else {
        int o = atomicAdd(ovf_cnt, 1);
        ovf[o] = i;   // ovf sized N: cannot overflow
    }
}

// ---------------- producer/consumer slab deposit ----------------
// Tile = (x, y0..y0+1, all z). LDS: buf[2][8ch][CSTR], CSTR = TYS*n + 4.
// Strided tile order: tile = bid + s*grid -> concurrent blocks adjacent.

__global__ __launch_bounds__(BLK) void deposit_pc(
    const float4* __restrict__ binrec, const int* __restrict__ counts,
    float* __restrict__ out, int n, int nyg, int ntiles)
{
    extern __shared__ float lds[];
    const int tid = threadIdx.x;
    const int bid = blockIdx.x;
    const int grid = gridDim.x;
    const int plane = TYS * n;          // data floats per channel
    const int cstr = plane + 4;         // padded channel stride (floats)
    const int bufsz = 8 * cstr;         // floats per buffer
    const int q4 = plane >> 2;          // data float4s per channel
    const int half = n >> 1;
    const size_t n3 = (size_t)n * n * n;
    const bool producer = (tid < 128);
    const int ctid = tid - 128;

    int iter = 0;
    int pt = -1;   // previous tile index

    for (int t = bid; t < ntiles; t += grid, ++iter) {
        const int p = iter & 1;
        float* bufp = lds + p * bufsz;

        // ---- phase 1: producers zero buf[p]; consumers store tile pt from buf[p^1]
        if (producer) {
            nfloat4* z4 = (nfloat4*)bufp;
            const int nz4 = bufsz >> 2;
            for (int i = tid; i < nz4; i += 128)
                z4[i] = (nfloat4)(0.f);
        } else if (iter > 0) {
            const float* src = lds + (p ^ 1) * bufsz;
            const int px_ = pt / nyg, pyg = pt - px_ * nyg;
            const int py0 = pyg * TYS;
            float* outb = out + (size_t)px_ * n * n + (size_t)py0 * n;
            #pragma unroll
            for (int ch = 0; ch < 8; ++ch) {
                const nfloat4* s4 = (const nfloat4*)(src + ch * cstr);
                nfloat4* d4 = (nfloat4*)(outb + (size_t)ch * n3);
                for (int q = ctid; q < q4; q += 128)
                    __builtin_nontemporal_store(s4[q], d4 + q);
            }
        }
        block_sync_lds();

        // ---- phase 2: producers deposit into buf[p]
        if (producer) {
            const int x = t / nyg, yg = t - x * nyg;
            const int y0 = yg * TYS;

            // per-thread register meta over the 12 neighbor bins
            int base[12], pref[13];
            pref[0] = 0;
            #pragma unroll
            for (int j = 0; j < 12; ++j) {
                int dxb = j >> 2;            // 0..2 -> x-1..x+1
                int jy  = j & 3;             // 0..3 -> y0-1..y0+2
                int xb = x + dxb - 1; if (xb < 0) xb += n; else if (xb >= n) xb -= n;
                int yb = y0 - 1 + jy; if (yb < 0) yb += n; else if (yb >= n) yb -= n;
                int bin = xb * n + yb;
                base[j] = bin * KColCAP;
                int c = counts[bin];
                c = (c < KColCAP) ? c : KColCAP;
                pref[j + 1] = pref[j] + c;
            }
            const int tot = pref[12];

            for (int v = tid; v < tot; v += 128) {
                // unrolled cndmask select of record index (no runtime reg-array idx)
                int rec = base[0] + v;
                #pragma unroll
                for (int k = 1; k < 12; ++k) {
                    int cand = base[k] + (v - pref[k]);
                    rec = (v >= pref[k]) ? cand : rec;
                }
                const float4* rp = binrec + (size_t)rec * 3;
                float4 P  = rp[0];
                float4 e0 = rp[1];
                float4 e1 = rp[2];

                int cx = (int)rintf(P.x); float dx = P.x - (float)cx;
                int cy = (int)rintf(P.y); float dy = P.y - (float)cy;
                int cz = (int)rintf(P.z); float dz = P.z - (float)cz;
                if (cx >= n) cx -= n; else if (cx < 0) cx += n;
                if (cy >= n) cy -= n; else if (cy < 0) cy += n;
                if (cz >= n) cz -= n; else if (cz < 0) cz += n;

                int rx = cx - x;  if (rx > half) rx -= n; else if (rx < -half) rx += n;
                int ry = cy - y0; if (ry > half) ry -= n; else if (ry < -half) ry += n;

                float wx = tsc_w(-rx, dx);   // single in-tile x corner

                float wys[3] = { wx * tsc_w(-1, dy), wx * tsc_w(0, dy), wx * tsc_w(1, dy) };
                float wzs[3] = { tsc_w(-1, dz), tsc_w(0, dz), tsc_w(1, dz) };
                int lz0 = cz - 1; if (lz0 < 0) lz0 += n;
                int lz2 = cz + 1; if (lz2 >= n) lz2 -= n;
                int lzs[3] = { lz0, cz, lz2 };

                #pragma unroll
                for (int kb = 0; kb < 3; ++kb) {
                    int ly = ry + kb - 1;
                    if (ly < 0 || ly >= TYS) continue;
                    float wvy = wys[kb];
                    #pragma unroll
                    for (int kc = 0; kc < 3; ++kc) {
                        float w = wvy * wzs[kc];
                        float* q = bufp + ly * n + lzs[kc];
                        atomicAdd(q + 0 * cstr, w * e0.x);
                        atomicAdd(q + 1 * cstr, w * e0.y);
                        atomicAdd(q + 2 * cstr, w * e0.z);
                        atomicAdd(q + 3 * cstr, w * e0.w);
                        atomicAdd(q + 4 * cstr, w * e1.x);
                        atomicAdd(q + 5 * cstr, w * e1.y);
                        atomicAdd(q + 6 * cstr, w * e1.z);
                        atomicAdd(q + 7 * cstr, w * e1.w);
                    }
                }
            }
        }
        block_sync_lds();
        pt = t;
    }

    // ---- epilogue: consumers store the final tile
    if (!producer && iter > 0) {
        const int p = (iter - 1) & 1;
        const float* src = lds + p * bufsz;
        const int px_ = pt / nyg, pyg = pt - px_ * nyg;
        const int py0 = pyg * TYS;
        float* outb = out + (size_t)px_ * n * n + (size_t)py0 * n;
        #pragma unroll
        for (int ch = 0; ch < 8; ++ch) {
            const nfloat4* s4 = (const nfloat4*)(src + ch * cstr);
            nfloat4* d4 = (nfloat4*)(outb + (size_t)ch * n3);
            for (int q = ctid; q < q4; q += 128)
                __builtin_nontemporal_store(s4[q], d4 + q);
        }
    }
}

// overflow cleanup: global planar atomics for atoms that missed their bin list
__global__ __launch_bounds__(256) void deposit_overflow(
    const float* __restrict__ pos, const float* __restrict__ cell,
    const float* __restrict__ emb, const int* __restrict__ ovf_cnt,
    const int* __restrict__ ovf, float* __restrict__ out, int n)
{
    int m = *ovf_cnt;
    int i = blockIdx.x * blockDim.x + threadIdx.x;
    if (i >= m) return;
    int ai = ovf[i];
    float inv_sp = inv_spacing(cell, n);
    float p[3], d[3]; int c0[3];
    #pragma unroll
    for (int kk = 0; kk < 3; ++kk) {
        p[kk] = pos[3 * ai + kk] * inv_sp;
        c0[kk] = (int)rintf(p[kk]);
        d[kk] = p[kk] - (float)c0[kk];
    }
    float w[3][3];
    #pragma unroll
    for (int kk = 0; kk < 3; ++kk) {
        float dd = d[kk];
        w[kk][0] = tsc_w(-1, dd); w[kk][1] = tsc_w(0, dd); w[kk][2] = tsc_w(1, dd);
    }
    int W[3][3];
    #pragma unroll
    for (int kk = 0; kk < 3; ++kk)
        #pragma unroll
        for (int a = 0; a < 3; ++a) {
            int v = c0[kk] - 1 + a; if (v < 0) v += n; else if (v >= n) v -= n;
            W[kk][a] = v;
        }
    size_t n3 = (size_t)n * n * n;
    const float4* e4 = (const float4*)(emb + (size_t)ai * 8);
    float4 e0 = e4[0], e1 = e4[1];
    float e[8] = {e0.x, e0.y, e0.z, e0.w, e1.x, e1.y, e1.z, e1.w};
    for (int a = 0; a < 3; ++a)
        for (int bq = 0; bq < 3; ++bq)
            for (int cq = 0; cq < 3; ++cq) {
                float wt = w[0][a] * w[1][bq] * w[2][cq];
                size_t g = ((size_t)W[0][a] * n + W[1][bq]) * n + W[2][cq];
                #pragma unroll
                for (int ch = 0; ch < 8; ++ch)
                    atomicAdd(out + (size_t)ch * n3 + g, wt * e[ch]);
            }
}

// ---------------- fallback: interleaved atomics + transpose ----------------

__global__ __launch_bounds__(256) void deposit_tsc8_ilv(
    const float* __restrict__ pos,
    const float* __restrict__ cell,
    const float* __restrict__ emb,
    float* __restrict__ ws,
    int total, int n)
{
    int t = blockIdx.x * blockDim.x + threadIdx.x;
    if (t >= total) return;
    int atom = t / 27;
    int c    = t - atom * 27;
    int a    = c / 9;
    int rem  = c - a * 9;
    int b    = rem / 3;
    int cc   = rem - b * 3;

    float inv_sp = inv_spacing(cell, n);

    float px = pos[3 * atom + 0] * inv_sp;
    float py = pos[3 * atom + 1] * inv_sp;
    float pz = pos[3 * atom + 2] * inv_sp;

    int cx = (int)rintf(px);  float dx = px - (float)cx;
    int cy = (int)rintf(py);  float dy = py - (float)cy;
    int cz = (int)rintf(pz);  float dz = pz - (float)cz;

    float w = tsc_w(a - 1, dx) * tsc_w(b - 1, dy) * tsc_w(cc - 1, dz);

    int x = cx - 1 + a;  if (x < 0) x += n; else if (x >= n) x -= n;
    int y = cy - 1 + b;  if (y < 0) y += n; else if (y >= n) y -= n;
    int z = cz - 1 + cc; if (z < 0) z += n; else if (z >= n) z -= n;

    const float4* e4 = (const float4*)(emb + (size_t)atom * 8);
    float4 e0 = e4[0], e1 = e4[1];

    float* p = ws + ((size_t)((x * n + y) * n + z)) * 8;
    atomicAdd(p + 0, w * e0.x);
    atomicAdd(p + 1, w * e0.y);
    atomicAdd(p + 2, w * e0.z);
    atomicAdd(p + 3, w * e0.w);
    atomicAdd(p + 4, w * e1.x);
    atomicAdd(p + 5, w * e1.y);
    atomicAdd(p + 6, w * e1.z);
    atomicAdd(p + 7, w * e1.w);
}

__global__ __launch_bounds__(256) void transpose_ilv8(
    const float* __restrict__ ws, float* __restrict__ out, int n3)
{
    int t = blockIdx.x * blockDim.x + threadIdx.x;
    int g0 = t * 4;
    if (g0 >= n3) return;
    const float4* w4 = (const float4*)(ws + (size_t)g0 * 8);
    float4 r0 = w4[0], r1 = w4[1];
    float4 r2 = w4[2], r3 = w4[3];
    float4 r4 = w4[4], r5 = w4[5];
    float4 r6 = w4[6], r7 = w4[7];

    *(float4*)(out + (size_t)0 * n3 + g0) = make_float4(r0.x, r2.x, r4.x, r6.x);
    *(float4*)(out + (size_t)1 * n3 + g0) = make_float4(r0.y, r2.y, r4.y, r6.y);
    *(float4*)(out + (size_t)2 * n3 + g0) = make_float4(r0.z, r2.z, r4.z, r6.z);
    *(float4*)(out + (size_t)3 * n3 + g0) = make_float4(r0.w, r2.w, r4.w, r6.w);
    *(float4*)(out + (size_t)4 * n3 + g0) = make_float4(r1.x, r3.x, r5.x, r7.x);
    *(float4*)(out + (size_t)5 * n3 + g0) = make_float4(r1.y, r3.y, r5.y, r7.y);
    *(float4*)(out + (size_t)6 * n3 + g0) = make_float4(r1.z, r3.z, r5.z, r7.z);
    *(float4*)(out + (size_t)7 * n3 + g0) = make_float4(r1.w, r3.w, r5.w, r7.w);
}

// ---------------- fallback: generic planar atomics ----------------

__global__ __launch_bounds__(256) void deposit_tsc_gen(
    const float* __restrict__ pos,
    const float* __restrict__ cell,
    const float* __restrict__ emb,
    float* __restrict__ out,
    int N, int n, int C)
{
    int i = blockIdx.x * blockDim.x + threadIdx.x;
    if (i >= N) return;

    float inv_sp = inv_spacing(cell, n);

    float p[3], d[3];
    int c0[3];
    #pragma unroll
    for (int k = 0; k < 3; ++k) {
        p[k] = pos[3 * i + k] * inv_sp;
        c0[k] = (int)rintf(p[k]);
        d[k] = p[k] - (float)c0[k];
    }
    float w[3][3];
    #pragma unroll
    for (int k = 0; k < 3; ++k) {
        float dd = d[k], d2 = dd * dd;
        w[k][0] = 0.125f * (1.0f - 4.0f * dd + 4.0f * d2);
        w[k][1] = 0.25f  * (3.0f - 4.0f * d2);
        w[k][2] = 0.125f * (1.0f + 4.0f * dd + 4.0f * d2);
    }
    int W[3][3];
    #pragma unroll
    for (int k = 0; k < 3; ++k) {
        #pragma unroll
        for (int a = 0; a < 3; ++a) {
            int v = c0[k] - 1 + a; if (v < 0) v += n; else if (v >= n) v -= n;
            W[k][a] = v;
        }
    }
    int n3 = n * n * n;
    for (int a = 0; a < 3; ++a)
        for (int b = 0; b < 3; ++b)
            for (int cc = 0; cc < 3; ++cc) {
                float wt = w[0][a] * w[1][b] * w[2][cc];
                int g = (W[0][a] * n + W[1][b]) * n + W[2][cc];
                for (int ch = 0; ch < C; ++ch)
                    atomicAdd(out + (size_t)ch * n3 + g, wt * emb[(size_t)i * C + ch]);
            }
}

extern "C" void kernel_launch(void* const* d_in, const int* in_sizes, int n_in,
                              void* d_out, int out_size, void* d_ws, size_t ws_size,
                              hipStream_t stream) {
    const float* pos  = (const float*)d_in[0];
    const float* cell = (const float*)d_in[1];
    const float* emb  = (const float*)d_in[2];
    float* out = (float*)d_out;
    float* ws  = (float*)d_ws;

    int N = in_sizes[0] / 3;
    int C = in_sizes[2] / N;
    long long n3l = (long long)out_size / C;
    int n = (int)llroundf(cbrtf((float)n3l));
    int n3 = (int)n3l;

    int block = 256;

    // ---- producer/consumer slab fast path ----
    {
        int nb = n * n;
        size_t lds_bytes = (size_t)2 * 8 * (TYS * n + 4) * sizeof(float);
        size_t rec_off = (((size_t)nb + 4 + (size_t)N) * sizeof(int) + 15) & ~(size_t)15;
        size_t need = rec_off + (size_t)nb * KColCAP * 48;
        bool ok = (C == 8) && (n % TYS == 0) && (n % 4 == 0) && n >= 8 && n <= 256
                  && lds_bytes <= 64 * 1024
                  && ws_size >= need
                  && ((long long)n * n * n == n3l);
        if (ok) {
            int* counts  = (int*)d_ws;
            int* ovf_cnt = counts + nb;
            int* ovf     = counts + nb + 4;
            float4* binrec = (float4*)((char*)d_ws + rec_off);

            (void)hipMemsetAsync(counts, 0, (size_t)(nb + 4) * sizeof(int), stream);
            fill_recs<<<(N + block - 1) / block, block, 0, stream>>>(
                pos, cell, emb, counts, ovf_cnt, binrec, ovf, N, n);

            int nyg = n / TYS;
            int ntiles = n * nyg;
            int nblocks = NBLK;
            if (nblocks > ntiles) nblocks = ntiles;
            deposit_pc<<<nblocks, BLK, lds_bytes, stream>>>(
                binrec, counts, out, n, nyg, ntiles);

            deposit_overflow<<<(N + block - 1) / block, block, 0, stream>>>(
                pos, cell, emb, ovf_cnt, ovf, out, n);
            return;
        }
    }

    // ---- fallback: interleaved atomics + transpose ----
    size_t need = (size_t)out_size * sizeof(float);
    if (C == 8 && ws_size >= need && (n3 % 4) == 0) {
        (void)hipMemsetAsync(d_ws, 0, need, stream);
        int total = N * 27;
        deposit_tsc8_ilv<<<(total + block - 1) / block, block, 0, stream>>>(
            pos, cell, emb, ws, total, n);
        int tthreads = n3 / 4;
        transpose_ilv8<<<(tthreads + block - 1) / block, block, 0, stream>>>(
            ws, out, n3);
    } else {
        (void)hipMemsetAsync(d_out, 0, (size_t)out_size * sizeof(float), stream);
        int grid = (N + block - 1) / block;
        deposit_tsc_gen<<<grid, block, 0, stream>>>(pos, cell, emb, out, N, n, C);
    }
}